// Round 3
// baseline (962.959 us; speedup 1.0000x reference)
//
#include <hip/hip_runtime.h>
#include <hip/hip_bf16.h>

static constexpr float NEG_SLOPE = 0.01f;
static constexpr float BN_EPS = 1e-5f;

// ---------------------------------------------------------------------------
// diagnostic: if workspace is too small, flood output with 1e6 so the
// harness-printed absmax error tells us ws_size was the problem.
__global__ __launch_bounds__(256) void sentinel_kernel(float* out, int m, float val) {
  int i = blockIdx.x * 256 + threadIdx.x;
  if (i < m) out[i] = val;
}

// zero deg (n ints) + stats (256 floats: [0:128) layer0, [128:256) layer1)
__global__ __launch_bounds__(256) void zero_kernel(int* __restrict__ deg,
                                                   float* __restrict__ stats, int n) {
  int stride = gridDim.x * blockDim.x;
  for (int i = blockIdx.x * blockDim.x + threadIdx.x; i < n; i += stride) deg[i] = 0;
  if (blockIdx.x == 0 && threadIdx.x < 256) stats[threadIdx.x] = 0.f;
}

// deg[v] = #incoming edges (targets)
__global__ __launch_bounds__(256) void deg_kernel(const int* __restrict__ col,
                                                  int* __restrict__ deg, int E) {
  int stride = gridDim.x * blockDim.x;
  for (int i = blockIdx.x * blockDim.x + threadIdx.x; i < E; i += stride)
    atomicAdd(&deg[col[i]], 1);
}

// dis[v] = rsqrt(deg[v] + 1)   (+1 = self loop; matches ref deg over col+loops)
__global__ __launch_bounds__(256) void dis_kernel(const int* __restrict__ deg,
                                                  float* __restrict__ dis, int n) {
  int stride = gridDim.x * blockDim.x;
  for (int i = blockIdx.x * blockDim.x + threadIdx.x; i < n; i += stride)
    dis[i] = rsqrtf((float)(deg[i] + 1));
}

// ---------------------------------------------------------------------------
// g[r,c] = (X[r,:] @ W[:,c]) * dis[r].  One thread per output element.
// wave = one row (r uniform per wave), lane = column c. W staged in LDS.
template <int KD>
__global__ __launch_bounds__(256) void gemm_simple(
    const float* __restrict__ X, const float* __restrict__ W,
    const float* __restrict__ dis, float* __restrict__ g, int n) {
  __shared__ float sW[KD * 64];
  for (int i = threadIdx.x; i < KD * 64; i += 256) sW[i] = W[i];
  __syncthreads();
  int gid = blockIdx.x * 256 + threadIdx.x;
  if (gid >= n * 64) return;
  int r = gid >> 6;
  int c = gid & 63;
  const float* xp = X + (size_t)r * KD;
  float s = 0.f;
#pragma unroll 8
  for (int k = 0; k < KD; ++k) s = fmaf(xp[k], sW[k * 64 + c], s);
  g[gid] = s * dis[r];
}

// dst = src (float4), used to seed acc with the self-loop term g[v]
__global__ __launch_bounds__(256) void copy_kernel(const float4* __restrict__ src,
                                                   float4* __restrict__ dst, int m4) {
  int stride = gridDim.x * blockDim.x;
  for (int i = blockIdx.x * blockDim.x + threadIdx.x; i < m4; i += stride) dst[i] = src[i];
}

// acc[col[e],:] += g[row[e],:]   — one wave per edge, lane = feature
__global__ __launch_bounds__(256) void scatter_kernel(
    const int* __restrict__ row, const int* __restrict__ colv,
    const float* __restrict__ g, float* __restrict__ acc, int E) {
  int lane = threadIdx.x & 63;
  int wid = (blockIdx.x * 256 + threadIdx.x) >> 6;
  int nw = (gridDim.x * 256) >> 6;
  for (int e = wid; e < E; e += nw) {
    int u = row[e];
    int v = colv[e];
    atomicAdd(&acc[(size_t)v * 64 + lane], g[(size_t)u * 64 + lane]);
  }
}

// acc <- leaky(dis[v]*acc + b[d]); accumulate per-feature sum/sumsq into stats
__global__ __launch_bounds__(256) void post1_kernel(
    float* __restrict__ acc, const float* __restrict__ dis,
    const float* __restrict__ bias, float* __restrict__ stats, int n) {
  const int tid = threadIdx.x;
  const int d = tid & 63;
  const float bd = bias[d];
  float lsum = 0.f, lsq = 0.f;
  const int total = n * 64;
  const int stride = gridDim.x * 256;
  for (int i = blockIdx.x * 256 + tid; i < total; i += stride) {
    int v = i >> 6;
    float t = dis[v] * acc[i] + bd;
    t = (t > 0.f) ? t : NEG_SLOPE * t;
    acc[i] = t;
    lsum += t;
    lsq += t * t;
  }
  __shared__ float red[256];
  red[tid] = lsum;
  __syncthreads();
  if (tid < 64) atomicAdd(&stats[d], red[tid] + red[tid + 64] + red[tid + 128] + red[tid + 192]);
  __syncthreads();
  red[tid] = lsq;
  __syncthreads();
  if (tid < 64) atomicAdd(&stats[64 + d], red[tid] + red[tid + 64] + red[tid + 128] + red[tid + 192]);
}

// in-place BN: h = (h - mu) * rstd * gamma + beta
__global__ __launch_bounds__(256) void bn_kernel(
    float* h, const float* __restrict__ stats, const float* __restrict__ gamma,
    const float* __restrict__ beta, int n) {
  __shared__ float sc[64], sh[64];
  if (threadIdx.x < 64) {
    int d = threadIdx.x;
    float inv_n = 1.0f / (float)n;
    float mu = stats[d] * inv_n;
    float var = stats[64 + d] * inv_n - mu * mu;
    float r = rsqrtf(var + BN_EPS);
    float s = gamma[d] * r;
    sc[d] = s;
    sh[d] = beta[d] - mu * s;
  }
  __syncthreads();
  const int total4 = n * 16;
  const int stride = gridDim.x * 256;
  for (int i = blockIdx.x * 256 + threadIdx.x; i < total4; i += stride) {
    float4 tv = reinterpret_cast<float4*>(h)[i];
    int d0 = (i * 4) & 63;
    tv.x = tv.x * sc[d0] + sh[d0];
    tv.y = tv.y * sc[d0 + 1] + sh[d0 + 1];
    tv.z = tv.z * sc[d0 + 2] + sh[d0 + 2];
    tv.w = tv.w * sc[d0 + 3] + sh[d0 + 3];
    reinterpret_cast<float4*>(h)[i] = tv;
  }
}

// out[k,d] = h[idx[k], d]  (f32)
__global__ __launch_bounds__(256) void sel_kernel(const float* __restrict__ h,
                                                  const int* __restrict__ idx,
                                                  float* __restrict__ out, int K) {
  int gid = blockIdx.x * 256 + threadIdx.x;
  if (gid >= K * 64) return;
  int k = gid >> 6;
  int d = gid & 63;
  out[gid] = h[(size_t)idx[k] * 64 + d];
}

// out2[k,j] = sigmoid(h[idx[k],:] @ Wm[:,j] + bm[j])  (f32)
__global__ __launch_bounds__(256) void mlp_kernel(const float* __restrict__ h,
                                                  const int* __restrict__ idx,
                                                  const float* __restrict__ Wm,
                                                  const float* __restrict__ bm,
                                                  float* __restrict__ out2, int K) {
  int gid = blockIdx.x * 256 + threadIdx.x;
  if (gid >= K * 5) return;
  int k = gid / 5;
  int j = gid - 5 * k;
  const float* hp = h + (size_t)idx[k] * 64;
  float s = bm[j];
#pragma unroll
  for (int d = 0; d < 64; ++d) s = fmaf(hp[d], Wm[d * 5 + j], s);
  out2[gid] = 1.f / (1.f + expf(-s));
}

// ---------------------------------------------------------------------------
extern "C" void kernel_launch(void* const* d_in, const int* in_sizes, int n_in,
                              void* d_out, int out_size, void* d_ws, size_t ws_size,
                              hipStream_t stream) {
  const float* x      = (const float*)d_in[0];
  const int*   eidx   = (const int*)d_in[1];
  const int*   idx    = (const int*)d_in[2];
  const float* W0     = (const float*)d_in[3];
  const float* b0     = (const float*)d_in[4];
  const float* gamma0 = (const float*)d_in[5];
  const float* beta0  = (const float*)d_in[6];
  const float* W1     = (const float*)d_in[7];
  const float* b1     = (const float*)d_in[8];
  const float* gamma1 = (const float*)d_in[9];
  const float* beta1  = (const float*)d_in[10];
  const float* Wm     = (const float*)d_in[11];
  const float* bm     = (const float*)d_in[12];

  const int n = in_sizes[0] / 128;
  const int E = in_sizes[1] / 2;
  const int K = in_sizes[2];
  const int* erow = eidx;      // sources  (edge_index[0])
  const int* ecol = eidx + E;  // targets  (edge_index[1])

  // workspace: 2 feature buffers + dis + deg + stats  (~52 MB)
  size_t needed = 2 * (size_t)n * 64 * 4 + (size_t)n * 4 + (size_t)n * 4 + 256 * 4;
  if (ws_size < needed) {
    sentinel_kernel<<<dim3((out_size + 255) / 256), dim3(256), 0, stream>>>(
        (float*)d_out, out_size, 1e6f);
    return;
  }
  float* buf0 = (float*)d_ws;                 // g
  float* buf1 = buf0 + (size_t)n * 64;        // acc / t / h (in-place)
  float* dis  = buf1 + (size_t)n * 64;        // n
  int*   deg  = (int*)(dis + n);              // n
  float* stats = (float*)(deg + n);           // 256

  dim3 blk(256);
  zero_kernel<<<dim3((n + 255) / 256), blk, 0, stream>>>(deg, stats, n);
  deg_kernel<<<dim3(2048), blk, 0, stream>>>(ecol, deg, E);
  dis_kernel<<<dim3((n + 255) / 256), blk, 0, stream>>>(deg, dis, n);

  const int gemm_blocks = (n * 64 + 255) / 256;
  const int m4 = n * 16;

  // ---- layer 0 ----
  gemm_simple<128><<<dim3(gemm_blocks), blk, 0, stream>>>(x, W0, dis, buf0, n);
  copy_kernel<<<dim3(2048), blk, 0, stream>>>((const float4*)buf0, (float4*)buf1, m4);
  scatter_kernel<<<dim3(2048), blk, 0, stream>>>(erow, ecol, buf0, buf1, E);
  post1_kernel<<<dim3(2048), blk, 0, stream>>>(buf1, dis, b0, stats, n);
  bn_kernel<<<dim3(2048), blk, 0, stream>>>(buf1, stats, gamma0, beta0, n);
  // ---- layer 1 ----
  gemm_simple<64><<<dim3(gemm_blocks), blk, 0, stream>>>(buf1, W1, dis, buf0, n);
  copy_kernel<<<dim3(2048), blk, 0, stream>>>((const float4*)buf0, (float4*)buf1, m4);
  scatter_kernel<<<dim3(2048), blk, 0, stream>>>(erow, ecol, buf0, buf1, E);
  post1_kernel<<<dim3(2048), blk, 0, stream>>>(buf1, dis, b1, stats + 128, n);
  bn_kernel<<<dim3(2048), blk, 0, stream>>>(buf1, stats + 128, gamma1, beta1, n);
  // ---- select + MLP ----
  sel_kernel<<<dim3((K * 64 + 255) / 256), blk, 0, stream>>>(buf1, idx, (float*)d_out, K);
  mlp_kernel<<<dim3((K * 5 + 255) / 256), blk, 0, stream>>>(
      buf1, idx, Wm, bm, (float*)d_out + (size_t)K * 64, K);
}

// Round 4
// 657.560 us; speedup vs baseline: 1.4644x; 1.4644x over previous
//
#include <hip/hip_runtime.h>
#include <hip/hip_bf16.h>

static constexpr float NEG_SLOPE = 0.01f;
static constexpr float BN_EPS = 1e-5f;

// ---------------------------------------------------------------------------
__global__ __launch_bounds__(256) void sentinel_kernel(float* out, int m, float val) {
  int i = blockIdx.x * 256 + threadIdx.x;
  if (i < m) out[i] = val;
}

// zero deg (n ints) + stats (256 floats)
__global__ __launch_bounds__(256) void zero_kernel(int* __restrict__ deg,
                                                   float* __restrict__ stats, int n) {
  int stride = gridDim.x * blockDim.x;
  for (int i = blockIdx.x * blockDim.x + threadIdx.x; i < n; i += stride) deg[i] = 0;
  if (blockIdx.x == 0 && threadIdx.x < 256) stats[threadIdx.x] = 0.f;
}

// deg[v] = #incoming edges (targets)
__global__ __launch_bounds__(256) void deg_kernel(const int* __restrict__ col,
                                                  int* __restrict__ deg, int E) {
  int stride = gridDim.x * blockDim.x;
  for (int i = blockIdx.x * blockDim.x + threadIdx.x; i < E; i += stride)
    atomicAdd(&deg[col[i]], 1);
}

// ---------------------------------------------------------------------------
// 3-phase exclusive scan of deg -> start, plus dis = rsqrt(deg+1)
__global__ __launch_bounds__(256) void scan_partial(const int* __restrict__ deg,
                                                    int* __restrict__ partial, int n) {
  int i = blockIdx.x * 256 + threadIdx.x;
  int v = (i < n) ? deg[i] : 0;
  __shared__ int s[256];
  s[threadIdx.x] = v;
  __syncthreads();
  for (int off = 128; off; off >>= 1) {
    if (threadIdx.x < off) s[threadIdx.x] += s[threadIdx.x + off];
    __syncthreads();
  }
  if (threadIdx.x == 0) partial[blockIdx.x] = s[0];
}

// single-block exclusive scan of partial[nb] in place
__global__ __launch_bounds__(256) void scan_top(int* partial, int nb) {
  __shared__ int s[256];
  __shared__ int carry_s;
  if (threadIdx.x == 0) carry_s = 0;
  __syncthreads();
  for (int base = 0; base < nb; base += 256) {
    int i = base + threadIdx.x;
    int v = (i < nb) ? partial[i] : 0;
    s[threadIdx.x] = v;
    __syncthreads();
    for (int off = 1; off < 256; off <<= 1) {
      int t = (threadIdx.x >= off) ? s[threadIdx.x - off] : 0;
      __syncthreads();
      s[threadIdx.x] += t;
      __syncthreads();
    }
    int inc = s[threadIdx.x];
    int tot = s[255];
    int carry = carry_s;
    if (i < nb) partial[i] = carry + inc - v;
    __syncthreads();
    if (threadIdx.x == 0) carry_s = carry + tot;
    __syncthreads();
  }
}

__global__ __launch_bounds__(256) void scan_final(const int* __restrict__ deg,
                                                  const int* __restrict__ partial,
                                                  int* __restrict__ start,
                                                  float* __restrict__ dis, int n, int E) {
  int i = blockIdx.x * 256 + threadIdx.x;
  int v = (i < n) ? deg[i] : 0;
  __shared__ int s[256];
  s[threadIdx.x] = v;
  __syncthreads();
  for (int off = 1; off < 256; off <<= 1) {
    int t = (threadIdx.x >= off) ? s[threadIdx.x - off] : 0;
    __syncthreads();
    s[threadIdx.x] += t;
    __syncthreads();
  }
  if (i < n) {
    start[i] = partial[blockIdx.x] + s[threadIdx.x] - v;
    dis[i] = rsqrtf((float)(v + 1));
  }
  if (i == 0) start[n] = E;
}

// csr[start[v] + slot] = row[e]; slot via atomicSub on deg (destroys deg -> 0)
__global__ __launch_bounds__(256) void fill_kernel(
    const int* __restrict__ row, const int* __restrict__ colv,
    const int* __restrict__ start, int* __restrict__ deg,
    int* __restrict__ csr, int E) {
  int stride = gridDim.x * blockDim.x;
  for (int e = blockIdx.x * blockDim.x + threadIdx.x; e < E; e += stride) {
    int v = colv[e];
    int o = atomicSub(&deg[v], 1) - 1;
    csr[start[v] + o] = row[e];
  }
}

// ---------------------------------------------------------------------------
// g[r,c] = (X[r,:] @ W[:,c]) * dis[r]. Wave = 4 rows, lane = col, W in LDS.
template <int KD>
__global__ __launch_bounds__(256) void gemm_tiled(
    const float* __restrict__ X, const float* __restrict__ W,
    const float* __restrict__ dis, float* __restrict__ g, int n) {
  __shared__ float sW[KD * 64];
  for (int i = threadIdx.x; i < KD * 64; i += 256) sW[i] = W[i];
  __syncthreads();
  const int lane = threadIdx.x & 63;
  const int wq = threadIdx.x >> 6;
  int r0 = blockIdx.x * 16 + wq * 4;
  if (r0 >= n) return;
  float acc0 = 0.f, acc1 = 0.f, acc2 = 0.f, acc3 = 0.f;
  if (r0 + 4 <= n) {
    const float* xp = X + (size_t)r0 * KD;
#pragma unroll 4
    for (int k0 = 0; k0 < KD; k0 += 4) {
      float4 x0 = *reinterpret_cast<const float4*>(xp + k0);
      float4 x1 = *reinterpret_cast<const float4*>(xp + KD + k0);
      float4 x2 = *reinterpret_cast<const float4*>(xp + 2 * KD + k0);
      float4 x3 = *reinterpret_cast<const float4*>(xp + 3 * KD + k0);
      float w0 = sW[(k0 + 0) * 64 + lane];
      float w1 = sW[(k0 + 1) * 64 + lane];
      float w2 = sW[(k0 + 2) * 64 + lane];
      float w3 = sW[(k0 + 3) * 64 + lane];
      acc0 = fmaf(x0.x, w0, acc0); acc0 = fmaf(x0.y, w1, acc0);
      acc0 = fmaf(x0.z, w2, acc0); acc0 = fmaf(x0.w, w3, acc0);
      acc1 = fmaf(x1.x, w0, acc1); acc1 = fmaf(x1.y, w1, acc1);
      acc1 = fmaf(x1.z, w2, acc1); acc1 = fmaf(x1.w, w3, acc1);
      acc2 = fmaf(x2.x, w0, acc2); acc2 = fmaf(x2.y, w1, acc2);
      acc2 = fmaf(x2.z, w2, acc2); acc2 = fmaf(x2.w, w3, acc2);
      acc3 = fmaf(x3.x, w0, acc3); acc3 = fmaf(x3.y, w1, acc3);
      acc3 = fmaf(x3.z, w2, acc3); acc3 = fmaf(x3.w, w3, acc3);
    }
    g[(size_t)(r0 + 0) * 64 + lane] = acc0 * dis[r0 + 0];
    g[(size_t)(r0 + 1) * 64 + lane] = acc1 * dis[r0 + 1];
    g[(size_t)(r0 + 2) * 64 + lane] = acc2 * dis[r0 + 2];
    g[(size_t)(r0 + 3) * 64 + lane] = acc3 * dis[r0 + 3];
  } else {
    for (int j = 0; j < 4 && r0 + j < n; ++j) {
      float s = 0.f;
      for (int k = 0; k < KD; ++k)
        s = fmaf(X[(size_t)(r0 + j) * KD + k], sW[k * 64 + lane], s);
      g[(size_t)(r0 + j) * 64 + lane] = s * dis[r0 + j];
    }
  }
}

// ---------------------------------------------------------------------------
// h[v] = leaky(dis[v]*(g[v] + sum_{u in CSR[v]} g[u]) + bias); stats sum/sumsq.
// One wave per node (grid-stride), lane = feature. No atomics on features.
__global__ __launch_bounds__(256) void gather_post(
    const float* __restrict__ g, const int* __restrict__ csr,
    const int* __restrict__ start, const float* __restrict__ dis,
    const float* __restrict__ bias, float* __restrict__ h,
    float* __restrict__ stats, int n) {
  const int lane = threadIdx.x & 63;
  const float bd = bias[lane];
  const int wid = (blockIdx.x * 256 + threadIdx.x) >> 6;
  const int nw = (gridDim.x * 256) >> 6;
  float lsum = 0.f, lsq = 0.f;
  for (int v = wid; v < n; v += nw) {
    int s0 = start[v];
    int s1 = start[v + 1];
    float sum = g[(size_t)v * 64 + lane];  // self loop
    for (int e = s0; e < s1; ++e) {
      int u = __builtin_amdgcn_readfirstlane(csr[e]);
      sum += g[(size_t)u * 64 + lane];
    }
    float t = dis[v] * sum + bd;
    t = (t > 0.f) ? t : NEG_SLOPE * t;
    h[(size_t)v * 64 + lane] = t;
    lsum += t;
    lsq += t * t;
  }
  __shared__ float red[256];
  red[threadIdx.x] = lsum;
  __syncthreads();
  if (threadIdx.x < 64)
    atomicAdd(&stats[lane],
              red[threadIdx.x] + red[threadIdx.x + 64] + red[threadIdx.x + 128] + red[threadIdx.x + 192]);
  __syncthreads();
  red[threadIdx.x] = lsq;
  __syncthreads();
  if (threadIdx.x < 64)
    atomicAdd(&stats[64 + lane],
              red[threadIdx.x] + red[threadIdx.x + 64] + red[threadIdx.x + 128] + red[threadIdx.x + 192]);
}

// in-place BN: h = (h - mu) * rstd * gamma + beta
__global__ __launch_bounds__(256) void bn_kernel(
    float* h, const float* __restrict__ stats, const float* __restrict__ gamma,
    const float* __restrict__ beta, int n) {
  __shared__ float sc[64], sh[64];
  if (threadIdx.x < 64) {
    int d = threadIdx.x;
    float inv_n = 1.0f / (float)n;
    float mu = stats[d] * inv_n;
    float var = stats[64 + d] * inv_n - mu * mu;
    float r = rsqrtf(var + BN_EPS);
    float s = gamma[d] * r;
    sc[d] = s;
    sh[d] = beta[d] - mu * s;
  }
  __syncthreads();
  const int total4 = n * 16;
  const int stride = gridDim.x * 256;
  for (int i = blockIdx.x * 256 + threadIdx.x; i < total4; i += stride) {
    float4 tv = reinterpret_cast<float4*>(h)[i];
    int d0 = (i * 4) & 63;
    tv.x = tv.x * sc[d0] + sh[d0];
    tv.y = tv.y * sc[d0 + 1] + sh[d0 + 1];
    tv.z = tv.z * sc[d0 + 2] + sh[d0 + 2];
    tv.w = tv.w * sc[d0 + 3] + sh[d0 + 3];
    reinterpret_cast<float4*>(h)[i] = tv;
  }
}

// out[k,d] = h[idx[k], d]
__global__ __launch_bounds__(256) void sel_kernel(const float* __restrict__ h,
                                                  const int* __restrict__ idx,
                                                  float* __restrict__ out, int K) {
  int gid = blockIdx.x * 256 + threadIdx.x;
  if (gid >= K * 64) return;
  int k = gid >> 6;
  int d = gid & 63;
  out[gid] = h[(size_t)idx[k] * 64 + d];
}

// out2[k,j] = sigmoid(h[idx[k],:] @ Wm[:,j] + bm[j])
__global__ __launch_bounds__(256) void mlp_kernel(const float* __restrict__ h,
                                                  const int* __restrict__ idx,
                                                  const float* __restrict__ Wm,
                                                  const float* __restrict__ bm,
                                                  float* __restrict__ out2, int K) {
  int gid = blockIdx.x * 256 + threadIdx.x;
  if (gid >= K * 5) return;
  int k = gid / 5;
  int j = gid - 5 * k;
  const float* hp = h + (size_t)idx[k] * 64;
  float s = bm[j];
#pragma unroll
  for (int d = 0; d < 64; ++d) s = fmaf(hp[d], Wm[d * 5 + j], s);
  out2[gid] = 1.f / (1.f + expf(-s));
}

// ---------------------------------------------------------------------------
extern "C" void kernel_launch(void* const* d_in, const int* in_sizes, int n_in,
                              void* d_out, int out_size, void* d_ws, size_t ws_size,
                              hipStream_t stream) {
  const float* x      = (const float*)d_in[0];
  const int*   eidx   = (const int*)d_in[1];
  const int*   idx    = (const int*)d_in[2];
  const float* W0     = (const float*)d_in[3];
  const float* b0     = (const float*)d_in[4];
  const float* gamma0 = (const float*)d_in[5];
  const float* beta0  = (const float*)d_in[6];
  const float* W1     = (const float*)d_in[7];
  const float* b1     = (const float*)d_in[8];
  const float* gamma1 = (const float*)d_in[9];
  const float* beta1  = (const float*)d_in[10];
  const float* Wm     = (const float*)d_in[11];
  const float* bm     = (const float*)d_in[12];

  const int n = in_sizes[0] / 128;
  const int E = in_sizes[1] / 2;
  const int K = in_sizes[2];
  const int* erow = eidx;      // sources  (edge_index[0])
  const int* ecol = eidx + E;  // targets  (edge_index[1])
  const int nb = (n + 255) / 256;

  size_t needed = 2 * (size_t)n * 64 * 4      // buf0, buf1
                + (size_t)n * 4               // dis
                + (size_t)n * 4               // deg
                + (size_t)(n + 1) * 4         // start
                + (size_t)E * 4               // csr
                + (size_t)(nb + 1) * 4        // partial
                + 256 * 4;                    // stats
  if (ws_size < needed) {
    sentinel_kernel<<<dim3((out_size + 255) / 256), dim3(256), 0, stream>>>(
        (float*)d_out, out_size, 1e6f);
    return;
  }
  float* buf0  = (float*)d_ws;                 // g
  float* buf1  = buf0 + (size_t)n * 64;        // h (in-place BN)
  float* dis   = buf1 + (size_t)n * 64;        // n
  int*   deg   = (int*)(dis + n);              // n (destroyed by fill)
  int*   start = deg + n;                      // n+1
  int*   csr   = start + (n + 1);              // E
  int*   partial = csr + E;                    // nb
  float* stats = (float*)(partial + nb + 1);   // 256

  dim3 blk(256);
  // ---- graph preprocessing: deg -> start (scan) -> csr ----
  zero_kernel<<<dim3(nb), blk, 0, stream>>>(deg, stats, n);
  deg_kernel<<<dim3(2048), blk, 0, stream>>>(ecol, deg, E);
  scan_partial<<<dim3(nb), blk, 0, stream>>>(deg, partial, n);
  scan_top<<<dim3(1), blk, 0, stream>>>(partial, nb);
  scan_final<<<dim3(nb), blk, 0, stream>>>(deg, partial, start, dis, n, E);
  fill_kernel<<<dim3(2048), blk, 0, stream>>>(erow, ecol, start, deg, csr, E);

  const int gemm_blocks = (n + 15) / 16;
  // ---- layer 0 ----
  gemm_tiled<128><<<dim3(gemm_blocks), blk, 0, stream>>>(x, W0, dis, buf0, n);
  gather_post<<<dim3(2048), blk, 0, stream>>>(buf0, csr, start, dis, b0, buf1, stats, n);
  bn_kernel<<<dim3(2048), blk, 0, stream>>>(buf1, stats, gamma0, beta0, n);
  // ---- layer 1 ----
  gemm_tiled<64><<<dim3(gemm_blocks), blk, 0, stream>>>(buf1, W1, dis, buf0, n);
  gather_post<<<dim3(2048), blk, 0, stream>>>(buf0, csr, start, dis, b1, buf1, stats + 128, n);
  bn_kernel<<<dim3(2048), blk, 0, stream>>>(buf1, stats + 128, gamma1, beta1, n);
  // ---- select + MLP ----
  sel_kernel<<<dim3((K * 64 + 255) / 256), blk, 0, stream>>>(buf1, idx, (float*)d_out, K);
  mlp_kernel<<<dim3((K * 5 + 255) / 256), blk, 0, stream>>>(
      buf1, idx, Wm, bm, (float*)d_out + (size_t)K * 64, K);
}

// Round 5
// 572.306 us; speedup vs baseline: 1.6826x; 1.1490x over previous
//
#include <hip/hip_runtime.h>
#include <hip/hip_bf16.h>

static constexpr float NEG_SLOPE = 0.01f;
static constexpr float BN_EPS = 1e-5f;

// ---------------------------------------------------------------------------
__global__ __launch_bounds__(256) void sentinel_kernel(float* out, int m, float val) {
  int i = blockIdx.x * 256 + threadIdx.x;
  if (i < m) out[i] = val;
}

// zero deg (n ints) + stats (256 floats)
__global__ __launch_bounds__(256) void zero_kernel(int* __restrict__ deg,
                                                   float* __restrict__ stats, int n) {
  int stride = gridDim.x * blockDim.x;
  for (int i = blockIdx.x * blockDim.x + threadIdx.x; i < n; i += stride) deg[i] = 0;
  if (blockIdx.x == 0 && threadIdx.x < 256) stats[threadIdx.x] = 0.f;
}

// deg[v] = #incoming edges (targets)
__global__ __launch_bounds__(256) void deg_kernel(const int* __restrict__ col,
                                                  int* __restrict__ deg, int E) {
  int stride = gridDim.x * blockDim.x;
  for (int i = blockIdx.x * blockDim.x + threadIdx.x; i < E; i += stride)
    atomicAdd(&deg[col[i]], 1);
}

// ---------------------------------------------------------------------------
// 3-phase exclusive scan of deg -> start, plus dis = rsqrt(deg+1)
__global__ __launch_bounds__(256) void scan_partial(const int* __restrict__ deg,
                                                    int* __restrict__ partial, int n) {
  int i = blockIdx.x * 256 + threadIdx.x;
  int v = (i < n) ? deg[i] : 0;
  __shared__ int s[256];
  s[threadIdx.x] = v;
  __syncthreads();
  for (int off = 128; off; off >>= 1) {
    if (threadIdx.x < off) s[threadIdx.x] += s[threadIdx.x + off];
    __syncthreads();
  }
  if (threadIdx.x == 0) partial[blockIdx.x] = s[0];
}

// single-block exclusive scan of partial[nb] in place
__global__ __launch_bounds__(256) void scan_top(int* partial, int nb) {
  __shared__ int s[256];
  __shared__ int carry_s;
  if (threadIdx.x == 0) carry_s = 0;
  __syncthreads();
  for (int base = 0; base < nb; base += 256) {
    int i = base + threadIdx.x;
    int v = (i < nb) ? partial[i] : 0;
    s[threadIdx.x] = v;
    __syncthreads();
    for (int off = 1; off < 256; off <<= 1) {
      int t = (threadIdx.x >= off) ? s[threadIdx.x - off] : 0;
      __syncthreads();
      s[threadIdx.x] += t;
      __syncthreads();
    }
    int inc = s[threadIdx.x];
    int tot = s[255];
    int carry = carry_s;
    if (i < nb) partial[i] = carry + inc - v;
    __syncthreads();
    if (threadIdx.x == 0) carry_s = carry + tot;
    __syncthreads();
  }
}

__global__ __launch_bounds__(256) void scan_final(const int* __restrict__ deg,
                                                  const int* __restrict__ partial,
                                                  int* __restrict__ start,
                                                  float* __restrict__ dis, int n, int E) {
  int i = blockIdx.x * 256 + threadIdx.x;
  int v = (i < n) ? deg[i] : 0;
  __shared__ int s[256];
  s[threadIdx.x] = v;
  __syncthreads();
  for (int off = 1; off < 256; off <<= 1) {
    int t = (threadIdx.x >= off) ? s[threadIdx.x - off] : 0;
    __syncthreads();
    s[threadIdx.x] += t;
    __syncthreads();
  }
  if (i < n) {
    start[i] = partial[blockIdx.x] + s[threadIdx.x] - v;
    dis[i] = rsqrtf((float)(v + 1));
  }
  if (i == 0) start[n] = E;
}

// csr[start[v] + slot] = row[e]; slot via atomicSub on deg (destroys deg -> 0)
__global__ __launch_bounds__(256) void fill_kernel(
    const int* __restrict__ row, const int* __restrict__ colv,
    const int* __restrict__ start, int* __restrict__ deg,
    int* __restrict__ csr, int E) {
  int stride = gridDim.x * blockDim.x;
  for (int e = blockIdx.x * blockDim.x + threadIdx.x; e < E; e += stride) {
    int v = colv[e];
    int o = atomicSub(&deg[v], 1) - 1;
    csr[start[v] + o] = row[e];
  }
}

// ---------------------------------------------------------------------------
// g[r,c] = (X[r,:] @ W[:,c]) * dis[r]. Wave = 8 rows, lane = col, W in LDS.
template <int KD>
__global__ __launch_bounds__(256) void gemm_tiled(
    const float* __restrict__ X, const float* __restrict__ W,
    const float* __restrict__ dis, float* __restrict__ g, int n) {
  __shared__ float sW[KD * 64];
  for (int i = threadIdx.x; i < KD * 64; i += 256) sW[i] = W[i];
  __syncthreads();
  const int lane = threadIdx.x & 63;
  const int wq = threadIdx.x >> 6;
  int r0 = blockIdx.x * 32 + wq * 8;
  if (r0 >= n) return;
  float acc[8];
#pragma unroll
  for (int j = 0; j < 8; ++j) acc[j] = 0.f;
  if (r0 + 8 <= n) {
    const float* xp = X + (size_t)r0 * KD;
#pragma unroll 2
    for (int k0 = 0; k0 < KD; k0 += 4) {
      float4 xr[8];
#pragma unroll
      for (int j = 0; j < 8; ++j)
        xr[j] = *reinterpret_cast<const float4*>(xp + (size_t)j * KD + k0);
      float w0 = sW[(k0 + 0) * 64 + lane];
      float w1 = sW[(k0 + 1) * 64 + lane];
      float w2 = sW[(k0 + 2) * 64 + lane];
      float w3 = sW[(k0 + 3) * 64 + lane];
#pragma unroll
      for (int j = 0; j < 8; ++j) {
        acc[j] = fmaf(xr[j].x, w0, acc[j]);
        acc[j] = fmaf(xr[j].y, w1, acc[j]);
        acc[j] = fmaf(xr[j].z, w2, acc[j]);
        acc[j] = fmaf(xr[j].w, w3, acc[j]);
      }
    }
#pragma unroll
    for (int j = 0; j < 8; ++j)
      g[(size_t)(r0 + j) * 64 + lane] = acc[j] * dis[r0 + j];
  } else {
    for (int j = 0; j < 8 && r0 + j < n; ++j) {
      float s = 0.f;
      for (int k = 0; k < KD; ++k)
        s = fmaf(X[(size_t)(r0 + j) * KD + k], sW[k * 64 + lane], s);
      g[(size_t)(r0 + j) * 64 + lane] = s * dis[r0 + j];
    }
  }
}

// ---------------------------------------------------------------------------
// h[v] = leaky(dis[v]*(g[v] + sum_{u in CSR[v]} g[u]) + bias); stats sum/sumsq.
// One wave per node (grid-stride), lane = feature. 8-wide unrolled edge loop
// -> 8 independent 256B gathers in flight (latency hiding).
__global__ __launch_bounds__(256) void gather_post(
    const float* __restrict__ g, const int* __restrict__ csr,
    const int* __restrict__ start, const float* __restrict__ dis,
    const float* __restrict__ bias, float* __restrict__ h,
    float* __restrict__ stats, int n) {
  const int lane = threadIdx.x & 63;
  const float bd = bias[lane];
  const int wid = (blockIdx.x * 256 + threadIdx.x) >> 6;
  const int nw = (gridDim.x * 256) >> 6;
  float lsum = 0.f, lsq = 0.f;
  for (int v = wid; v < n; v += nw) {
    int s0 = start[v];
    int s1 = start[v + 1];
    float sum = g[(size_t)v * 64 + lane];  // self loop
    int e = s0;
    int nfull = s0 + ((s1 - s0) & ~7);
    for (; e < nfull; e += 8) {
      int u0 = csr[e + 0], u1 = csr[e + 1], u2 = csr[e + 2], u3 = csr[e + 3];
      int u4 = csr[e + 4], u5 = csr[e + 5], u6 = csr[e + 6], u7 = csr[e + 7];
      float a0 = g[(size_t)u0 * 64 + lane];
      float a1 = g[(size_t)u1 * 64 + lane];
      float a2 = g[(size_t)u2 * 64 + lane];
      float a3 = g[(size_t)u3 * 64 + lane];
      float a4 = g[(size_t)u4 * 64 + lane];
      float a5 = g[(size_t)u5 * 64 + lane];
      float a6 = g[(size_t)u6 * 64 + lane];
      float a7 = g[(size_t)u7 * 64 + lane];
      sum += ((a0 + a1) + (a2 + a3)) + ((a4 + a5) + (a6 + a7));
    }
    if (e < s1) {
      float part = 0.f;
      for (; e < s1; ++e) {
        int u = csr[e];
        part += g[(size_t)u * 64 + lane];
      }
      sum += part;
    }
    float t = dis[v] * sum + bd;
    t = (t > 0.f) ? t : NEG_SLOPE * t;
    h[(size_t)v * 64 + lane] = t;
    lsum += t;
    lsq += t * t;
  }
  __shared__ float red[256];
  red[threadIdx.x] = lsum;
  __syncthreads();
  if (threadIdx.x < 64)
    atomicAdd(&stats[lane],
              red[threadIdx.x] + red[threadIdx.x + 64] + red[threadIdx.x + 128] + red[threadIdx.x + 192]);
  __syncthreads();
  red[threadIdx.x] = lsq;
  __syncthreads();
  if (threadIdx.x < 64)
    atomicAdd(&stats[64 + lane],
              red[threadIdx.x] + red[threadIdx.x + 64] + red[threadIdx.x + 128] + red[threadIdx.x + 192]);
}

// in-place BN: h = (h - mu) * rstd * gamma + beta
__global__ __launch_bounds__(256) void bn_kernel(
    float* h, const float* __restrict__ stats, const float* __restrict__ gamma,
    const float* __restrict__ beta, int n) {
  __shared__ float sc[64], sh[64];
  if (threadIdx.x < 64) {
    int d = threadIdx.x;
    float inv_n = 1.0f / (float)n;
    float mu = stats[d] * inv_n;
    float var = stats[64 + d] * inv_n - mu * mu;
    float r = rsqrtf(var + BN_EPS);
    float s = gamma[d] * r;
    sc[d] = s;
    sh[d] = beta[d] - mu * s;
  }
  __syncthreads();
  const int total4 = n * 16;
  const int stride = gridDim.x * 256;
  for (int i = blockIdx.x * 256 + threadIdx.x; i < total4; i += stride) {
    float4 tv = reinterpret_cast<float4*>(h)[i];
    int d0 = (i * 4) & 63;
    tv.x = tv.x * sc[d0] + sh[d0];
    tv.y = tv.y * sc[d0 + 1] + sh[d0 + 1];
    tv.z = tv.z * sc[d0 + 2] + sh[d0 + 2];
    tv.w = tv.w * sc[d0 + 3] + sh[d0 + 3];
    reinterpret_cast<float4*>(h)[i] = tv;
  }
}

// fused: out[k,:] = h[idx[k],:];  out2[k,j] = sigmoid(h[idx[k],:]@Wm[:,j]+bm[j])
// one wave per k, lane = feature; 5 dots via shuffle reduction.
__global__ __launch_bounds__(256) void selmlp_kernel(
    const float* __restrict__ h, const int* __restrict__ idx,
    const float* __restrict__ Wm, const float* __restrict__ bm,
    float* __restrict__ out, float* __restrict__ out2, int K) {
  const int lane = threadIdx.x & 63;
  int w = (blockIdx.x * 256 + threadIdx.x) >> 6;
  if (w >= K) return;
  int v = idx[w];
  float hv = h[(size_t)v * 64 + lane];
  out[(size_t)w * 64 + lane] = hv;
#pragma unroll
  for (int j = 0; j < 5; ++j) {
    float p = hv * Wm[lane * 5 + j];
#pragma unroll
    for (int off = 32; off; off >>= 1) p += __shfl_xor(p, off);
    if (lane == 0) out2[(size_t)w * 5 + j] = 1.f / (1.f + expf(-(p + bm[j])));
  }
}

// ---------------------------------------------------------------------------
extern "C" void kernel_launch(void* const* d_in, const int* in_sizes, int n_in,
                              void* d_out, int out_size, void* d_ws, size_t ws_size,
                              hipStream_t stream) {
  const float* x      = (const float*)d_in[0];
  const int*   eidx   = (const int*)d_in[1];
  const int*   idx    = (const int*)d_in[2];
  const float* W0     = (const float*)d_in[3];
  const float* b0     = (const float*)d_in[4];
  const float* gamma0 = (const float*)d_in[5];
  const float* beta0  = (const float*)d_in[6];
  const float* W1     = (const float*)d_in[7];
  const float* b1     = (const float*)d_in[8];
  const float* gamma1 = (const float*)d_in[9];
  const float* beta1  = (const float*)d_in[10];
  const float* Wm     = (const float*)d_in[11];
  const float* bm     = (const float*)d_in[12];

  const int n = in_sizes[0] / 128;
  const int E = in_sizes[1] / 2;
  const int K = in_sizes[2];
  const int* erow = eidx;      // sources  (edge_index[0])
  const int* ecol = eidx + E;  // targets  (edge_index[1])
  const int nb = (n + 255) / 256;

  size_t needed = 2 * (size_t)n * 64 * 4      // buf0, buf1
                + (size_t)n * 4               // dis
                + (size_t)n * 4               // deg
                + (size_t)(n + 1) * 4         // start
                + (size_t)E * 4               // csr
                + (size_t)(nb + 1) * 4        // partial
                + 256 * 4;                    // stats
  if (ws_size < needed) {
    sentinel_kernel<<<dim3((out_size + 255) / 256), dim3(256), 0, stream>>>(
        (float*)d_out, out_size, 1e6f);
    return;
  }
  float* buf0  = (float*)d_ws;                 // g
  float* buf1  = buf0 + (size_t)n * 64;        // h (in-place BN)
  float* dis   = buf1 + (size_t)n * 64;        // n
  int*   deg   = (int*)(dis + n);              // n (destroyed by fill)
  int*   start = deg + n;                      // n+1
  int*   csr   = start + (n + 1);              // E
  int*   partial = csr + E;                    // nb
  float* stats = (float*)(partial + nb + 1);   // 256

  dim3 blk(256);
  // ---- graph preprocessing: deg -> start (scan) -> csr ----
  zero_kernel<<<dim3(nb), blk, 0, stream>>>(deg, stats, n);
  deg_kernel<<<dim3(2048), blk, 0, stream>>>(ecol, deg, E);
  scan_partial<<<dim3(nb), blk, 0, stream>>>(deg, partial, n);
  scan_top<<<dim3(1), blk, 0, stream>>>(partial, nb);
  scan_final<<<dim3(nb), blk, 0, stream>>>(deg, partial, start, dis, n, E);
  fill_kernel<<<dim3(2048), blk, 0, stream>>>(erow, ecol, start, deg, csr, E);

  const int gemm_blocks = (n + 31) / 32;
  // ---- layer 0 ----
  gemm_tiled<128><<<dim3(gemm_blocks), blk, 0, stream>>>(x, W0, dis, buf0, n);
  gather_post<<<dim3(2048), blk, 0, stream>>>(buf0, csr, start, dis, b0, buf1, stats, n);
  bn_kernel<<<dim3(2048), blk, 0, stream>>>(buf1, stats, gamma0, beta0, n);
  // ---- layer 1 ----
  gemm_tiled<64><<<dim3(gemm_blocks), blk, 0, stream>>>(buf1, W1, dis, buf0, n);
  gather_post<<<dim3(2048), blk, 0, stream>>>(buf0, csr, start, dis, b1, buf1, stats + 128, n);
  bn_kernel<<<dim3(2048), blk, 0, stream>>>(buf1, stats + 128, gamma1, beta1, n);
  // ---- select + MLP (fused) ----
  selmlp_kernel<<<dim3((K + 3) / 4), blk, 0, stream>>>(
      buf1, idx, Wm, bm, (float*)d_out, (float*)d_out + (size_t)K * 64, K);
}

// Round 6
// 481.031 us; speedup vs baseline: 2.0019x; 1.1898x over previous
//
#include <hip/hip_runtime.h>
#include <hip/hip_bf16.h>
#include <hip/hip_fp16.h>

static constexpr float NEG_SLOPE = 0.01f;
static constexpr float BN_EPS = 1e-5f;

// ---------------------------------------------------------------------------
__global__ __launch_bounds__(256) void sentinel_kernel(float* out, int m, float val) {
  int i = blockIdx.x * 256 + threadIdx.x;
  if (i < m) out[i] = val;
}

// zero deg (n ints) + stats (256 floats) + csr pad (16 ints at csr[E..E+16))
__global__ __launch_bounds__(256) void zero_kernel(int* __restrict__ deg,
                                                   float* __restrict__ stats,
                                                   int* __restrict__ csr_pad, int n) {
  int stride = gridDim.x * blockDim.x;
  for (int i = blockIdx.x * blockDim.x + threadIdx.x; i < n; i += stride) deg[i] = 0;
  if (blockIdx.x == 0 && threadIdx.x < 256) stats[threadIdx.x] = 0.f;
  if (blockIdx.x == 0 && threadIdx.x < 16) csr_pad[threadIdx.x] = 0;
}

// deg[v] = #incoming edges (targets)
__global__ __launch_bounds__(256) void deg_kernel(const int* __restrict__ col,
                                                  int* __restrict__ deg, int E) {
  int stride = gridDim.x * blockDim.x;
  for (int i = blockIdx.x * blockDim.x + threadIdx.x; i < E; i += stride)
    atomicAdd(&deg[col[i]], 1);
}

// ---------------------------------------------------------------------------
// 3-phase exclusive scan of deg -> start, plus dis = rsqrt(deg+1)
__global__ __launch_bounds__(256) void scan_partial(const int* __restrict__ deg,
                                                    int* __restrict__ partial, int n) {
  int i = blockIdx.x * 256 + threadIdx.x;
  int v = (i < n) ? deg[i] : 0;
  __shared__ int s[256];
  s[threadIdx.x] = v;
  __syncthreads();
  for (int off = 128; off; off >>= 1) {
    if (threadIdx.x < off) s[threadIdx.x] += s[threadIdx.x + off];
    __syncthreads();
  }
  if (threadIdx.x == 0) partial[blockIdx.x] = s[0];
}

// single-block exclusive scan of partial[nb] in place
__global__ __launch_bounds__(256) void scan_top(int* partial, int nb) {
  __shared__ int s[256];
  __shared__ int carry_s;
  if (threadIdx.x == 0) carry_s = 0;
  __syncthreads();
  for (int base = 0; base < nb; base += 256) {
    int i = base + threadIdx.x;
    int v = (i < nb) ? partial[i] : 0;
    s[threadIdx.x] = v;
    __syncthreads();
    for (int off = 1; off < 256; off <<= 1) {
      int t = (threadIdx.x >= off) ? s[threadIdx.x - off] : 0;
      __syncthreads();
      s[threadIdx.x] += t;
      __syncthreads();
    }
    int inc = s[threadIdx.x];
    int tot = s[255];
    int carry = carry_s;
    if (i < nb) partial[i] = carry + inc - v;
    __syncthreads();
    if (threadIdx.x == 0) carry_s = carry + tot;
    __syncthreads();
  }
}

__global__ __launch_bounds__(256) void scan_final(const int* __restrict__ deg,
                                                  const int* __restrict__ partial,
                                                  int* __restrict__ start,
                                                  float* __restrict__ dis, int n, int E) {
  int i = blockIdx.x * 256 + threadIdx.x;
  int v = (i < n) ? deg[i] : 0;
  __shared__ int s[256];
  s[threadIdx.x] = v;
  __syncthreads();
  for (int off = 1; off < 256; off <<= 1) {
    int t = (threadIdx.x >= off) ? s[threadIdx.x - off] : 0;
    __syncthreads();
    s[threadIdx.x] += t;
    __syncthreads();
  }
  if (i < n) {
    start[i] = partial[blockIdx.x] + s[threadIdx.x] - v;
    dis[i] = rsqrtf((float)(v + 1));
  }
  if (i == 0) start[n] = E;
}

// csr[start[v] + slot] = row[e]; slot via atomicSub on deg (destroys deg -> 0)
__global__ __launch_bounds__(256) void fill_kernel(
    const int* __restrict__ row, const int* __restrict__ colv,
    const int* __restrict__ start, int* __restrict__ deg,
    int* __restrict__ csr, int E) {
  int stride = gridDim.x * blockDim.x;
  for (int e = blockIdx.x * blockDim.x + threadIdx.x; e < E; e += stride) {
    int v = colv[e];
    int o = atomicSub(&deg[v], 1) - 1;
    csr[start[v] + o] = row[e];
  }
}

// ---------------------------------------------------------------------------
// g[r,c] = ((X[r,:] (*sc) @ W[:,c]) + c[c]) * dis[r], stored fp16.
// FOLD=true applies the folded BatchNorm of the previous layer:
//   sW[k][c] = W[k][c]*sc[k] staged in LDS; epilogue adds cadd[c].
template <int KD, bool FOLD>
__global__ __launch_bounds__(256) void gemm_tiled(
    const float* __restrict__ X, const float* __restrict__ W,
    const float* __restrict__ sc, const float* __restrict__ cadd,
    const float* __restrict__ dis, __half* __restrict__ g, int n) {
  __shared__ float sW[KD * 64];
  for (int i = threadIdx.x; i < KD * 64; i += 256) {
    float w = W[i];
    if (FOLD) w *= sc[i >> 6];
    sW[i] = w;
  }
  __syncthreads();
  const int lane = threadIdx.x & 63;
  const int wq = threadIdx.x >> 6;
  int r0 = blockIdx.x * 32 + wq * 8;
  if (r0 >= n) return;
  const float cl = FOLD ? cadd[lane] : 0.f;
  float acc[8];
#pragma unroll
  for (int j = 0; j < 8; ++j) acc[j] = 0.f;
  if (r0 + 8 <= n) {
    const float* xp = X + (size_t)r0 * KD;
#pragma unroll 2
    for (int k0 = 0; k0 < KD; k0 += 4) {
      float4 xr[8];
#pragma unroll
      for (int j = 0; j < 8; ++j)
        xr[j] = *reinterpret_cast<const float4*>(xp + (size_t)j * KD + k0);
      float w0 = sW[(k0 + 0) * 64 + lane];
      float w1 = sW[(k0 + 1) * 64 + lane];
      float w2 = sW[(k0 + 2) * 64 + lane];
      float w3 = sW[(k0 + 3) * 64 + lane];
#pragma unroll
      for (int j = 0; j < 8; ++j) {
        acc[j] = fmaf(xr[j].x, w0, acc[j]);
        acc[j] = fmaf(xr[j].y, w1, acc[j]);
        acc[j] = fmaf(xr[j].z, w2, acc[j]);
        acc[j] = fmaf(xr[j].w, w3, acc[j]);
      }
    }
#pragma unroll
    for (int j = 0; j < 8; ++j)
      g[(size_t)(r0 + j) * 64 + lane] = __float2half((acc[j] + cl) * dis[r0 + j]);
  } else {
    for (int j = 0; j < 8 && r0 + j < n; ++j) {
      float s = 0.f;
      for (int k = 0; k < KD; ++k)
        s = fmaf(X[(size_t)(r0 + j) * KD + k], sW[k * 64 + lane], s);
      g[(size_t)(r0 + j) * 64 + lane] = __float2half((s + cl) * dis[r0 + j]);
    }
  }
}

// ---------------------------------------------------------------------------
// t[v] = leaky(dis[v]*(g[v] + sum_{u in CSR[v]} g[u]) + bias); stats sum/sumsq.
// One wave per node, lane = feature. Masked 16-wide batches: ALL 16 gathers
// always in flight; out-of-range slots read g[v] (L1-hot) and are zeroed.
__global__ __launch_bounds__(256) void gather_post(
    const __half* __restrict__ g, const int* __restrict__ csr,
    const int* __restrict__ start, const float* __restrict__ dis,
    const float* __restrict__ bias, float* __restrict__ t_out,
    float* __restrict__ stats, int n) {
  const int lane = threadIdx.x & 63;
  const float bd = bias[lane];
  const int wid = (blockIdx.x * 256 + threadIdx.x) >> 6;
  const int nw = (gridDim.x * 256) >> 6;
  float lsum = 0.f, lsq = 0.f;
  for (int v = wid; v < n; v += nw) {
    int s0 = start[v];
    int s1 = start[v + 1];
    float sum = __half2float(g[(size_t)v * 64 + lane]);  // self loop
    for (int e = s0; e < s1; e += 16) {
      int u[16];
#pragma unroll
      for (int i = 0; i < 16; ++i) u[i] = (e + i < s1) ? csr[e + i] : v;
      float a[16];
#pragma unroll
      for (int i = 0; i < 16; ++i) a[i] = __half2float(g[(size_t)u[i] * 64 + lane]);
      float part = 0.f;
#pragma unroll
      for (int i = 0; i < 16; ++i) part += (e + i < s1) ? a[i] : 0.f;
      sum += part;
    }
    float t = dis[v] * sum + bd;
    t = (t > 0.f) ? t : NEG_SLOPE * t;
    t_out[(size_t)v * 64 + lane] = t;
    lsum += t;
    lsq += t * t;
  }
  __shared__ float red[256];
  red[threadIdx.x] = lsum;
  __syncthreads();
  if (threadIdx.x < 64)
    atomicAdd(&stats[lane],
              red[threadIdx.x] + red[threadIdx.x + 64] + red[threadIdx.x + 128] + red[threadIdx.x + 192]);
  __syncthreads();
  red[threadIdx.x] = lsq;
  __syncthreads();
  if (threadIdx.x < 64)
    atomicAdd(&stats[64 + lane],
              red[threadIdx.x] + red[threadIdx.x + 64] + red[threadIdx.x + 128] + red[threadIdx.x + 192]);
}

// ---------------------------------------------------------------------------
// BN fold params: sc[d]=gamma*rstd, sh[d]=beta-mu*sc; if W!=null also
// c[j] = sum_k sh[k]*W[k,j] (the constant row the folded GEMM adds).
__global__ __launch_bounds__(64) void bnparam_kernel(
    const float* __restrict__ stats, const float* __restrict__ gamma,
    const float* __restrict__ beta, const float* __restrict__ W,
    float* __restrict__ outp, int n, int withC) {
  int d = threadIdx.x;
  __shared__ float ssh[64];
  float inv_n = 1.0f / (float)n;
  float mu = stats[d] * inv_n;
  float var = stats[64 + d] * inv_n - mu * mu;
  float r = rsqrtf(var + BN_EPS);
  float s = gamma[d] * r;
  float sh = beta[d] - mu * s;
  outp[d] = s;
  outp[64 + d] = sh;
  ssh[d] = sh;
  __syncthreads();
  if (withC) {
    float c = 0.f;
    for (int k = 0; k < 64; ++k) c = fmaf(ssh[k], W[k * 64 + d], c);
    outp[128 + d] = c;
  }
}

// fused: h_sel = t[idx]*sc1+sh1 (BN applied on the fly); out2 = sigmoid(h_sel@Wm+bm)
__global__ __launch_bounds__(256) void selmlp_kernel(
    const float* __restrict__ t, const int* __restrict__ idx,
    const float* __restrict__ bnp,  // sc1[0:64], sh1[64:128]
    const float* __restrict__ Wm, const float* __restrict__ bm,
    float* __restrict__ out, float* __restrict__ out2, int K) {
  const int lane = threadIdx.x & 63;
  int w = (blockIdx.x * 256 + threadIdx.x) >> 6;
  if (w >= K) return;
  int v = idx[w];
  float hv = fmaf(t[(size_t)v * 64 + lane], bnp[lane], bnp[64 + lane]);
  out[(size_t)w * 64 + lane] = hv;
#pragma unroll
  for (int j = 0; j < 5; ++j) {
    float p = hv * Wm[lane * 5 + j];
#pragma unroll
    for (int off = 32; off; off >>= 1) p += __shfl_xor(p, off);
    if (lane == 0) out2[(size_t)w * 5 + j] = 1.f / (1.f + expf(-(p + bm[j])));
  }
}

// ---------------------------------------------------------------------------
extern "C" void kernel_launch(void* const* d_in, const int* in_sizes, int n_in,
                              void* d_out, int out_size, void* d_ws, size_t ws_size,
                              hipStream_t stream) {
  const float* x      = (const float*)d_in[0];
  const int*   eidx   = (const int*)d_in[1];
  const int*   idx    = (const int*)d_in[2];
  const float* W0     = (const float*)d_in[3];
  const float* b0     = (const float*)d_in[4];
  const float* gamma0 = (const float*)d_in[5];
  const float* beta0  = (const float*)d_in[6];
  const float* W1     = (const float*)d_in[7];
  const float* b1     = (const float*)d_in[8];
  const float* gamma1 = (const float*)d_in[9];
  const float* beta1  = (const float*)d_in[10];
  const float* Wm     = (const float*)d_in[11];
  const float* bm     = (const float*)d_in[12];

  const int n = in_sizes[0] / 128;
  const int E = in_sizes[1] / 2;
  const int K = in_sizes[2];
  const int* erow = eidx;      // sources  (edge_index[0])
  const int* ecol = eidx + E;  // targets  (edge_index[1])
  const int nb = (n + 255) / 256;

  size_t needed = (size_t)n * 64 * 4          // tf (f32 activations)
                + 256 * 4 + 320 * 4           // stats + bn params
                + (size_t)n * 4               // dis
                + (size_t)n * 4               // deg
                + (size_t)(n + 1) * 4         // start
                + (size_t)(E + 16) * 4        // csr + pad
                + (size_t)(nb + 1) * 4        // partial
                + (size_t)n * 64 * 2;         // gh (fp16 g)
  if (ws_size < needed) {
    sentinel_kernel<<<dim3((out_size + 255) / 256), dim3(256), 0, stream>>>(
        (float*)d_out, out_size, 1e6f);
    return;
  }
  float* tf    = (float*)d_ws;                 // n*64 f32
  float* stats = tf + (size_t)n * 64;          // 256
  float* bnp   = stats + 256;                  // 320: sc0,sh0,c1,sc1,sh1
  float* dis   = bnp + 320;                    // n
  int*   deg   = (int*)(dis + n);              // n (destroyed by fill)
  int*   start = deg + n;                      // n+1
  int*   csr   = start + (n + 1);              // E+16
  int*   partial = csr + (E + 16);             // nb+1
  __half* gh   = (__half*)(partial + nb + 1);  // n*64 fp16

  dim3 blk(256);
  // ---- graph preprocessing: deg -> start (scan) -> csr ----
  zero_kernel<<<dim3(nb), blk, 0, stream>>>(deg, stats, csr + E, n);
  deg_kernel<<<dim3(2048), blk, 0, stream>>>(ecol, deg, E);
  scan_partial<<<dim3(nb), blk, 0, stream>>>(deg, partial, n);
  scan_top<<<dim3(1), blk, 0, stream>>>(partial, nb);
  scan_final<<<dim3(nb), blk, 0, stream>>>(deg, partial, start, dis, n, E);
  fill_kernel<<<dim3(2048), blk, 0, stream>>>(erow, ecol, start, deg, csr, E);

  const int gemm_blocks = (n + 31) / 32;
  // ---- layer 0 ----
  gemm_tiled<128, false><<<dim3(gemm_blocks), blk, 0, stream>>>(
      x, W0, nullptr, nullptr, dis, gh, n);
  gather_post<<<dim3(2048), blk, 0, stream>>>(gh, csr, start, dis, b0, tf, stats, n);
  bnparam_kernel<<<dim3(1), dim3(64), 0, stream>>>(stats, gamma0, beta0, W1, bnp, n, 1);
  // ---- layer 1 (BN0 folded into GEMM) ----
  gemm_tiled<64, true><<<dim3(gemm_blocks), blk, 0, stream>>>(
      tf, W1, bnp, bnp + 128, dis, gh, n);
  gather_post<<<dim3(2048), blk, 0, stream>>>(gh, csr, start, dis, b1, tf, stats + 128, n);
  bnparam_kernel<<<dim3(1), dim3(64), 0, stream>>>(
      stats + 128, gamma1, beta1, nullptr, bnp + 192, n, 0);
  // ---- select + MLP (BN1 folded in) ----
  selmlp_kernel<<<dim3((K + 3) / 4), blk, 0, stream>>>(
      tf, idx, bnp + 192, Wm, bm, (float*)d_out, (float*)d_out + (size_t)K * 64, K);
}

// Round 7
// 361.279 us; speedup vs baseline: 2.6654x; 1.3315x over previous
//
#include <hip/hip_runtime.h>

static constexpr float NEG_SLOPE = 0.01f;
static constexpr float BN_EPS = 1e-5f;

using f16 = _Float16;
using f16x4 = __attribute__((ext_vector_type(4))) _Float16;
using f32x4 = __attribute__((ext_vector_type(4))) float;

// ---------------------------------------------------------------------------
__global__ __launch_bounds__(256) void sentinel_kernel(float* out, int m, float val) {
  int i = blockIdx.x * 256 + threadIdx.x;
  if (i < m) out[i] = val;
}

// zero deg (n ints) + stats (256 floats) + csr pad
__global__ __launch_bounds__(256) void zero_kernel(int* __restrict__ deg,
                                                   float* __restrict__ stats,
                                                   int* __restrict__ csr_pad, int n) {
  int stride = gridDim.x * blockDim.x;
  for (int i = blockIdx.x * blockDim.x + threadIdx.x; i < n; i += stride) deg[i] = 0;
  if (blockIdx.x == 0 && threadIdx.x < 256) stats[threadIdx.x] = 0.f;
  if (blockIdx.x == 0 && threadIdx.x < 16) csr_pad[threadIdx.x] = 0;
}

// deg[v] = #incoming edges (targets)
__global__ __launch_bounds__(256) void deg_kernel(const int* __restrict__ col,
                                                  int* __restrict__ deg, int E) {
  int stride = gridDim.x * blockDim.x;
  for (int i = blockIdx.x * blockDim.x + threadIdx.x; i < E; i += stride)
    atomicAdd(&deg[col[i]], 1);
}

// ---------------------------------------------------------------------------
// 3-phase exclusive scan of deg -> start, plus dis = rsqrt(deg+1)
__global__ __launch_bounds__(256) void scan_partial(const int* __restrict__ deg,
                                                    int* __restrict__ partial, int n) {
  int i = blockIdx.x * 256 + threadIdx.x;
  int v = (i < n) ? deg[i] : 0;
  __shared__ int s[256];
  s[threadIdx.x] = v;
  __syncthreads();
  for (int off = 128; off; off >>= 1) {
    if (threadIdx.x < off) s[threadIdx.x] += s[threadIdx.x + off];
    __syncthreads();
  }
  if (threadIdx.x == 0) partial[blockIdx.x] = s[0];
}

__global__ __launch_bounds__(256) void scan_top(int* partial, int nb) {
  __shared__ int s[256];
  __shared__ int carry_s;
  if (threadIdx.x == 0) carry_s = 0;
  __syncthreads();
  for (int base = 0; base < nb; base += 256) {
    int i = base + threadIdx.x;
    int v = (i < nb) ? partial[i] : 0;
    s[threadIdx.x] = v;
    __syncthreads();
    for (int off = 1; off < 256; off <<= 1) {
      int t = (threadIdx.x >= off) ? s[threadIdx.x - off] : 0;
      __syncthreads();
      s[threadIdx.x] += t;
      __syncthreads();
    }
    int inc = s[threadIdx.x];
    int tot = s[255];
    int carry = carry_s;
    if (i < nb) partial[i] = carry + inc - v;
    __syncthreads();
    if (threadIdx.x == 0) carry_s = carry + tot;
    __syncthreads();
  }
}

__global__ __launch_bounds__(256) void scan_final(const int* __restrict__ deg,
                                                  const int* __restrict__ partial,
                                                  int* __restrict__ start,
                                                  float* __restrict__ dis, int n, int E) {
  int i = blockIdx.x * 256 + threadIdx.x;
  int v = (i < n) ? deg[i] : 0;
  __shared__ int s[256];
  s[threadIdx.x] = v;
  __syncthreads();
  for (int off = 1; off < 256; off <<= 1) {
    int t = (threadIdx.x >= off) ? s[threadIdx.x - off] : 0;
    __syncthreads();
    s[threadIdx.x] += t;
    __syncthreads();
  }
  if (i < n) {
    start[i] = partial[blockIdx.x] + s[threadIdx.x] - v;
    dis[i] = rsqrtf((float)(v + 1));
  }
  if (i == 0) start[n] = E;
}

// csr[start[v] + slot] = row[e]; slot via atomicSub on deg (destroys deg -> 0)
__global__ __launch_bounds__(256) void fill_kernel(
    const int* __restrict__ row, const int* __restrict__ colv,
    const int* __restrict__ start, int* __restrict__ deg,
    int* __restrict__ csr, int E) {
  int stride = gridDim.x * blockDim.x;
  for (int e = blockIdx.x * blockDim.x + threadIdx.x; e < E; e += stride) {
    int v = colv[e];
    int o = atomicSub(&deg[v], 1) - 1;
    csr[start[v] + o] = row[e];
  }
}

// ---------------------------------------------------------------------------
// MFMA GEMM: g[r,c] = ((A[r,:](*sc) @ W[:,c]) + cadd[c]) * dis[r], fp16 out.
// v_mfma_f32_16x16x16_f16; wave computes a 16-row x 64-col tile per iter.
// B (weights, optionally BN-folded) resident in registers for the whole block.
// A fragment: lane l -> row l%16, k = (l/16)*4 + j.  D: col l&15, row (l>>4)*4+v.
template <int KD, bool FOLD, bool A_HALF>
__global__ __launch_bounds__(256) void mfma_gemm(
    const void* __restrict__ Aptr, const float* __restrict__ W,
    const float* __restrict__ sc, const float* __restrict__ cadd,
    const float* __restrict__ dis, f16* __restrict__ g, int n) {
  constexpr int NKT = KD / 16;
  const int lane = threadIdx.x & 63;
  const int wq = threadIdx.x >> 6;
  const int lr = lane & 15;        // row-in-tile (A) / col-in-tile (B, D)
  const int kb = (lane >> 4) * 4;  // k-base within a 16-k tile

  // one-time: weight fragments into registers (64 VGPRs for KD=128)
  f16x4 bfrag[NKT][4];
#pragma unroll
  for (int kt = 0; kt < NKT; ++kt)
#pragma unroll
    for (int ct = 0; ct < 4; ++ct) {
#pragma unroll
      for (int j = 0; j < 4; ++j) {
        int k = kt * 16 + kb + j;
        float w = W[k * 64 + ct * 16 + lr];
        if (FOLD) w *= sc[k];
        bfrag[kt][ct][j] = (f16)w;
      }
    }
  float cl[4];
#pragma unroll
  for (int ct = 0; ct < 4; ++ct) cl[ct] = FOLD ? cadd[ct * 16 + lr] : 0.f;

  const int ntiles = (n + 15) >> 4;
  for (int t = blockIdx.x * 4 + wq; t < ntiles; t += gridDim.x * 4) {
    const int r0 = t << 4;
    int arow = r0 + lr;
    if (arow >= n) arow = n - 1;  // clamp; those D-rows are masked at store
    f16x4 afrag[NKT];
    if (A_HALF) {
      const f16* Ah = (const f16*)Aptr;
#pragma unroll
      for (int kt = 0; kt < NKT; ++kt)
        afrag[kt] = *reinterpret_cast<const f16x4*>(Ah + (size_t)arow * KD + kt * 16 + kb);
    } else {
      const float* Af = (const float*)Aptr;
#pragma unroll
      for (int kt = 0; kt < NKT; ++kt) {
        f32x4 xa = *reinterpret_cast<const f32x4*>(Af + (size_t)arow * KD + kt * 16 + kb);
        f16x4 a;
        a[0] = (f16)xa[0]; a[1] = (f16)xa[1]; a[2] = (f16)xa[2]; a[3] = (f16)xa[3];
        afrag[kt] = a;
      }
    }
    f32x4 acc[4];
#pragma unroll
    for (int ct = 0; ct < 4; ++ct) acc[ct] = (f32x4){0.f, 0.f, 0.f, 0.f};
#pragma unroll
    for (int kt = 0; kt < NKT; ++kt)
#pragma unroll
      for (int ct = 0; ct < 4; ++ct)
        acc[ct] = __builtin_amdgcn_mfma_f32_16x16x16f16(afrag[kt], bfrag[kt][ct], acc[ct], 0, 0, 0);
    if (r0 + 16 <= n) {
#pragma unroll
      for (int v = 0; v < 4; ++v) {
        int grow = r0 + (lane >> 4) * 4 + v;
        float dv = dis[grow];
#pragma unroll
        for (int ct = 0; ct < 4; ++ct)
          g[(size_t)grow * 64 + ct * 16 + lr] = (f16)((acc[ct][v] + cl[ct]) * dv);
      }
    } else {
      for (int v = 0; v < 4; ++v) {
        int grow = r0 + (lane >> 4) * 4 + v;
        if (grow < n) {
          float dv = dis[grow];
          for (int ct = 0; ct < 4; ++ct)
            g[(size_t)grow * 64 + ct * 16 + lr] = (f16)((acc[ct][v] + cl[ct]) * dv);
        }
      }
    }
  }
}

// ---------------------------------------------------------------------------
// t[v] = leaky(dis[v]*(g[v] + sum_{u in CSR[v]} g[u]) + bias); stats sum/sumsq.
// One wave per node, lane = feature. Masked 16-wide gather batches.
template <typename OutT>
__global__ __launch_bounds__(256) void gather_post(
    const f16* __restrict__ g, const int* __restrict__ csr,
    const int* __restrict__ start, const float* __restrict__ dis,
    const float* __restrict__ bias, OutT* __restrict__ t_out,
    float* __restrict__ stats, int n) {
  const int lane = threadIdx.x & 63;
  const float bd = bias[lane];
  const int wid = (blockIdx.x * 256 + threadIdx.x) >> 6;
  const int nw = (gridDim.x * 256) >> 6;
  float lsum = 0.f, lsq = 0.f;
  for (int v = wid; v < n; v += nw) {
    int s0 = start[v];
    int s1 = start[v + 1];
    float sum = (float)g[(size_t)v * 64 + lane];  // self loop
    for (int e = s0; e < s1; e += 16) {
      int u[16];
#pragma unroll
      for (int i = 0; i < 16; ++i) u[i] = (e + i < s1) ? csr[e + i] : v;
      float a[16];
#pragma unroll
      for (int i = 0; i < 16; ++i) a[i] = (float)g[(size_t)u[i] * 64 + lane];
      float part = 0.f;
#pragma unroll
      for (int i = 0; i < 16; ++i) part += (e + i < s1) ? a[i] : 0.f;
      sum += part;
    }
    float t = dis[v] * sum + bd;
    t = (t > 0.f) ? t : NEG_SLOPE * t;
    t_out[(size_t)v * 64 + lane] = (OutT)t;
    lsum += t;
    lsq += t * t;
  }
  __shared__ float red[256];
  red[threadIdx.x] = lsum;
  __syncthreads();
  if (threadIdx.x < 64)
    atomicAdd(&stats[lane],
              red[threadIdx.x] + red[threadIdx.x + 64] + red[threadIdx.x + 128] + red[threadIdx.x + 192]);
  __syncthreads();
  red[threadIdx.x] = lsq;
  __syncthreads();
  if (threadIdx.x < 64)
    atomicAdd(&stats[64 + lane],
              red[threadIdx.x] + red[threadIdx.x + 64] + red[threadIdx.x + 128] + red[threadIdx.x + 192]);
}

// ---------------------------------------------------------------------------
// BN fold params: sc[d]=gamma*rstd, sh[d]=beta-mu*sc; if withC also
// c[j] = sum_k sh[k]*W[k,j].
__global__ __launch_bounds__(64) void bnparam_kernel(
    const float* __restrict__ stats, const float* __restrict__ gamma,
    const float* __restrict__ beta, const float* __restrict__ W,
    float* __restrict__ outp, int n, int withC) {
  int d = threadIdx.x;
  __shared__ float ssh[64];
  float inv_n = 1.0f / (float)n;
  float mu = stats[d] * inv_n;
  float var = stats[64 + d] * inv_n - mu * mu;
  float r = rsqrtf(var + BN_EPS);
  float s = gamma[d] * r;
  float sh = beta[d] - mu * s;
  outp[d] = s;
  outp[64 + d] = sh;
  ssh[d] = sh;
  __syncthreads();
  if (withC) {
    float c = 0.f;
    for (int k = 0; k < 64; ++k) c = fmaf(ssh[k], W[k * 64 + d], c);
    outp[128 + d] = c;
  }
}

// fused: h_sel = t[idx]*sc1+sh1; out2 = sigmoid(h_sel@Wm+bm)
__global__ __launch_bounds__(256) void selmlp_kernel(
    const float* __restrict__ t, const int* __restrict__ idx,
    const float* __restrict__ bnp, const float* __restrict__ Wm,
    const float* __restrict__ bm, float* __restrict__ out,
    float* __restrict__ out2, int K) {
  const int lane = threadIdx.x & 63;
  int w = (blockIdx.x * 256 + threadIdx.x) >> 6;
  if (w >= K) return;
  int v = idx[w];
  float hv = fmaf(t[(size_t)v * 64 + lane], bnp[lane], bnp[64 + lane]);
  out[(size_t)w * 64 + lane] = hv;
#pragma unroll
  for (int j = 0; j < 5; ++j) {
    float p = hv * Wm[lane * 5 + j];
#pragma unroll
    for (int off = 32; off; off >>= 1) p += __shfl_xor(p, off);
    if (lane == 0) out2[(size_t)w * 5 + j] = 1.f / (1.f + expf(-(p + bm[j])));
  }
}

// ---------------------------------------------------------------------------
extern "C" void kernel_launch(void* const* d_in, const int* in_sizes, int n_in,
                              void* d_out, int out_size, void* d_ws, size_t ws_size,
                              hipStream_t stream) {
  const float* x      = (const float*)d_in[0];
  const int*   eidx   = (const int*)d_in[1];
  const int*   idx    = (const int*)d_in[2];
  const float* W0     = (const float*)d_in[3];
  const float* b0     = (const float*)d_in[4];
  const float* gamma0 = (const float*)d_in[5];
  const float* beta0  = (const float*)d_in[6];
  const float* W1     = (const float*)d_in[7];
  const float* b1     = (const float*)d_in[8];
  const float* gamma1 = (const float*)d_in[9];
  const float* beta1  = (const float*)d_in[10];
  const float* Wm     = (const float*)d_in[11];
  const float* bm     = (const float*)d_in[12];

  const int n = in_sizes[0] / 128;
  const int E = in_sizes[1] / 2;
  const int K = in_sizes[2];
  const int* erow = eidx;      // sources  (edge_index[0])
  const int* ecol = eidx + E;  // targets  (edge_index[1])
  const int nb = (n + 255) / 256;

  size_t needed = (size_t)n * 64 * 4          // tf (f32, layer-1 activations)
                + 256 * 4 + 320 * 4           // stats + bn params
                + (size_t)n * 4               // dis
                + (size_t)n * 4               // deg
                + (size_t)(n + 1) * 4         // start
                + (size_t)(E + 16) * 4        // csr + pad
                + (size_t)(nb + 1) * 4        // partial
                + (size_t)n * 64 * 2          // gh (fp16 g)
                + (size_t)n * 64 * 2;         // t0h (fp16 layer-0 activations)
  if (ws_size < needed) {
    sentinel_kernel<<<dim3((out_size + 255) / 256), dim3(256), 0, stream>>>(
        (float*)d_out, out_size, 1e6f);
    return;
  }
  float* tf    = (float*)d_ws;                 // n*64 f32
  float* stats = tf + (size_t)n * 64;          // 256
  float* bnp   = stats + 256;                  // 320: sc0,sh0,c1,sc1,sh1
  float* dis   = bnp + 320;                    // n
  int*   deg   = (int*)(dis + n);              // n (destroyed by fill)
  int*   start = deg + n;                      // n+1
  int*   csr   = start + (n + 1);              // E+16
  int*   partial = csr + (E + 16);             // nb+1
  f16*   gh    = (f16*)(partial + nb + 1);     // n*64 fp16
  f16*   t0h   = gh + (size_t)n * 64;          // n*64 fp16

  dim3 blk(256);
  // ---- graph preprocessing: deg -> start (scan) -> csr ----
  zero_kernel<<<dim3(nb), blk, 0, stream>>>(deg, stats, csr + E, n);
  deg_kernel<<<dim3(2048), blk, 0, stream>>>(ecol, deg, E);
  scan_partial<<<dim3(nb), blk, 0, stream>>>(deg, partial, n);
  scan_top<<<dim3(1), blk, 0, stream>>>(partial, nb);
  scan_final<<<dim3(nb), blk, 0, stream>>>(deg, partial, start, dis, n, E);
  fill_kernel<<<dim3(2048), blk, 0, stream>>>(erow, ecol, start, deg, csr, E);

  // ---- layer 0 ----
  mfma_gemm<128, false, false><<<dim3(640), blk, 0, stream>>>(
      x, W0, nullptr, nullptr, dis, gh, n);
  gather_post<f16><<<dim3(2048), blk, 0, stream>>>(gh, csr, start, dis, b0, t0h, stats, n);
  bnparam_kernel<<<dim3(1), dim3(64), 0, stream>>>(stats, gamma0, beta0, W1, bnp, n, 1);
  // ---- layer 1 (BN0 folded into GEMM) ----
  mfma_gemm<64, true, true><<<dim3(640), blk, 0, stream>>>(
      t0h, W1, bnp, bnp + 128, dis, gh, n);
  gather_post<float><<<dim3(2048), blk, 0, stream>>>(gh, csr, start, dis, b1, tf, stats + 128, n);
  bnparam_kernel<<<dim3(1), dim3(64), 0, stream>>>(
      stats + 128, gamma1, beta1, nullptr, bnp + 192, n, 0);
  // ---- select + MLP (BN1 folded in) ----
  selmlp_kernel<<<dim3((K + 3) / 4), blk, 0, stream>>>(
      tf, idx, bnp + 192, Wm, bm, (float*)d_out, (float*)d_out + (size_t)K * 64, K);
}